// Round 13
// baseline (2714.247 us; speedup 1.0000x reference)
//
#include <hip/hip_runtime.h>
#include <hip/hip_bf16.h>

// Problem constants (from reference)
#define BB    512
#define TT    128
#define HID   1024
#define EMBD  512
#define VOC   1024
#define OUTN  1024
#define DIMG  2048
#define FOURH 4096

typedef __attribute__((ext_vector_type(8))) short  short8;   // 8 bf16 (MFMA A/B frag)
typedef __attribute__((ext_vector_type(4))) float  f32x4;    // MFMA C/D frag
typedef unsigned int u32;

// Gate-interleaved column map: n' = G*64 + gate*16 + u -> original col = gate*1024 + G*16 + u
__device__ __forceinline__ int lstm_colmap(int n) {
    return ((n >> 4) & 3) * HID + ((n >> 6) << 4) + (n & 15);
}
__device__ __forceinline__ float sigmoidf_(float x) { return 1.0f / (1.0f + expf(-x)); }
__device__ __forceinline__ short f2bf(float x) { __hip_bfloat16 b = __float2bfloat16(x); return *(short*)&b; }
__device__ __forceinline__ float bf2f(short s) { __hip_bfloat16 b; *(short*)&b = s; return __bfloat162float(b); }

// async global->LDS, 16B per lane; lds base wave-uniform (HW adds lane*16)
__device__ __forceinline__ void async_cp16(void* lds, const void* g) {
    __builtin_amdgcn_global_load_lds((const __attribute__((address_space(1))) u32*)g,
                                     (__attribute__((address_space(3))) u32*)lds, 16, 0, 0);
}

// ---------------------------------------------------------------------------
// Merged setup: images f32->bf16, embed f32->bf16, state init + bias broadcast.
__global__ void setup_k(const float* __restrict__ images, short* __restrict__ imgs_c,
                        const float* __restrict__ embed,  short* __restrict__ embed_c,
                        float* __restrict__ c, short* __restrict__ h0,
                        float* __restrict__ o0, float* __restrict__ o1,
                        const float* __restrict__ bimg, const float* __restrict__ bhid) {
    int i = blockIdx.x * 256 + threadIdx.x;
    if (i < 262144) {                       // images: 512*2048/4
        float4 v = ((const float4*)images)[i];
        short4 o; o.x = f2bf(v.x); o.y = f2bf(v.y); o.z = f2bf(v.z); o.w = f2bf(v.w);
        ((short4*)imgs_c)[i] = o;
    } else if (i < 393216) {                // embed: 1024*512/4
        int k = i - 262144;
        float4 v = ((const float4*)embed)[k];
        short4 o; o.x = f2bf(v.x); o.y = f2bf(v.y); o.z = f2bf(v.z); o.w = f2bf(v.w);
        ((short4*)embed_c)[k] = o;
    } else {                                // state/out init: 512*1024
        int k = i - 393216;
        int n = k & (OUTN - 1);
        c[k] = 0.0f; h0[k] = 0;
        o0[k] = bimg[n]; o1[k] = bhid[n];
    }
}

// ---------------------------------------------------------------------------
// Merged tiled transposes: out[n][k] = bf16(in[k][map?(n)]), 32x32 tiles, 256 thr.
__global__ void tr_all_k(const float* __restrict__ Wc_h, short* __restrict__ Wh_t,
                         const float* __restrict__ Wc_x, short* __restrict__ Wx_t,
                         const float* __restrict__ Wimg, short* __restrict__ Wimg_t,
                         const float* __restrict__ Whid, short* __restrict__ Whid_t) {
    int id = blockIdx.x;
    const float* in; short* out; int K, N_in, bx, by; bool map;
    if (id < 4096)      { in = Wc_h; out = Wh_t;   K = 1024; N_in = 4096; map = true;  bx = id & 127;  by = id >> 7; }
    else if (id < 6144) { id -= 4096; in = Wc_x; out = Wx_t; K = 512;  N_in = 4096; map = true;  bx = id & 127;  by = id >> 7; }
    else if (id < 8192) { id -= 6144; in = Wimg; out = Wimg_t; K = 2048; N_in = 1024; map = false; bx = id & 31; by = id >> 5; }
    else                { id -= 8192; in = Whid; out = Whid_t; K = 1024; N_in = 1024; map = false; bx = id & 31; by = id >> 5; }

    __shared__ short tile[32][33];
    int n0 = bx * 32, k0 = by * 32;
    int tx = threadIdx.x & 31, ty = threadIdx.x >> 5;   // 32 x 8
    int nsrc = map ? lstm_colmap(n0 + tx) : (n0 + tx);
#pragma unroll
    for (int j = 0; j < 4; j++) {
        int kw = ty + j * 8;
        tile[kw][tx] = f2bf(in[(size_t)(k0 + kw) * N_in + nsrc]);
    }
    __syncthreads();
#pragma unroll
    for (int j = 0; j < 4; j++) {
        int nw = ty + j * 8;
        out[(size_t)(n0 + nw) * K + k0 + tx] = tile[tx][nw];
    }
}

// ---------------------------------------------------------------------------
// Double-buffered MFMA core, tile 64x128, BK=64, 4 waves 2x2 (R8/R9-verified; used
// for the three one-shot GEMMs only).
template<typename OutT, bool ATOMIC, bool MAPB>
__global__ __launch_bounds__(256) void gemm_bt_k(
    const short* __restrict__ A, const short* __restrict__ Bt,
    const float* __restrict__ bias, OutT* __restrict__ out,
    int Kf, int niter, int N)
{
    __shared__ __align__(16) short As[2][2][64 * 32];
    __shared__ __align__(16) short Bs[2][2][128 * 32];
    const int tid  = threadIdx.x;
    const int lane = tid & 63, wid = tid >> 6;
    const int wm = wid >> 1, wn = wid & 1;
    const int col16 = lane & 15, quad = lane >> 4;
    const int m0 = blockIdx.y * 64;
    const int n0 = blockIdx.x * 128;
    const int kbeg = blockIdx.z * niter * 64;

    const short* agp = A  + (size_t)(m0 + wid * 16 + (lane >> 2)) * Kf + kbeg + (lane & 3) * 8;
    const short* bgp = Bt + (size_t)(n0 + wid * 32 + (lane >> 2)) * Kf + kbeg + (lane & 3) * 8;

    f32x4 acc[2][4];
#pragma unroll
    for (int i = 0; i < 2; i++)
#pragma unroll
        for (int jj = 0; jj < 4; jj++) acc[i][jj] = (f32x4)0.0f;

    async_cp16(&As[0][0][wid * 512], agp);
    async_cp16(&As[0][1][wid * 512], agp + 32);
    async_cp16(&Bs[0][0][wid * 1024],       bgp);
    async_cp16(&Bs[0][0][wid * 1024 + 512], bgp + (size_t)16 * Kf);
    async_cp16(&Bs[0][1][wid * 1024],       bgp + 32);
    async_cp16(&Bs[0][1][wid * 1024 + 512], bgp + (size_t)16 * Kf + 32);
    __syncthreads();

    int buf = 0;
#pragma unroll 1
    for (int it = 0; it < niter; ++it) {
        if (it + 1 < niter) {
            int k0 = (it + 1) * 64;
            async_cp16(&As[buf ^ 1][0][wid * 512], agp + k0);
            async_cp16(&As[buf ^ 1][1][wid * 512], agp + k0 + 32);
            async_cp16(&Bs[buf ^ 1][0][wid * 1024],       bgp + k0);
            async_cp16(&Bs[buf ^ 1][0][wid * 1024 + 512], bgp + (size_t)16 * Kf + k0);
            async_cp16(&Bs[buf ^ 1][1][wid * 1024],       bgp + k0 + 32);
            async_cp16(&Bs[buf ^ 1][1][wid * 1024 + 512], bgp + (size_t)16 * Kf + k0 + 32);
        }
        short8 af[2][2], bf[4][2];
#pragma unroll
        for (int tr = 0; tr < 2; tr++)
#pragma unroll
            for (int p = 0; p < 2; p++)
                af[tr][p] = *(const short8*)&As[buf][p][(wm * 32 + tr * 16 + col16) * 32 + quad * 8];
#pragma unroll
        for (int tc = 0; tc < 4; tc++)
#pragma unroll
            for (int p = 0; p < 2; p++)
                bf[tc][p] = *(const short8*)&Bs[buf][p][(wn * 64 + tc * 16 + col16) * 32 + quad * 8];
#pragma unroll
        for (int p = 0; p < 2; p++)
#pragma unroll
            for (int tr = 0; tr < 2; tr++)
#pragma unroll
                for (int tc = 0; tc < 4; tc++)
                    acc[tr][tc] = __builtin_amdgcn_mfma_f32_16x16x32_bf16(af[tr][p], bf[tc][p], acc[tr][tc], 0, 0, 0);
        __syncthreads();
        buf ^= 1;
    }

#pragma unroll
    for (int tr = 0; tr < 2; tr++)
#pragma unroll
        for (int tc = 0; tc < 4; tc++) {
            int colg = n0 + wn * 64 + tc * 16 + col16;
            float bv = 0.0f;
            if constexpr (!ATOMIC) bv = bias[MAPB ? lstm_colmap(colg) : colg];
#pragma unroll
            for (int r = 0; r < 4; r++) {
                int rowg = m0 + wm * 32 + tr * 16 + quad * 4 + r;
                float v = acc[tr][tc][r] + bv;
                if constexpr (ATOMIC) atomicAdd((float*)&out[(size_t)rowg * N + colg], v);
                else                  out[(size_t)rowg * N + colg] = f2bf(v);
            }
        }
}

// ---------------------------------------------------------------------------
// LSTM step, barrier-free K-loop: the block's whole Wh slice (64 n' x 1024 k,
// 128 KB) is staged into LDS once per step (two halves; half2 staging overlaps
// the first 16 compute planes) -> only 2 barriers/step.  A (h_prev) is read
// global->reg inside the K-loop (per-quad rows give contiguous 64B segments);
// no barriers in the loop, latency hidden by unrolled ILP.
// LDS layout [k8][n'] with rotation n'_phys = (n + 2*(k8&3)) & 63:
//   read banks (4n + 8*quad) mod 32 -> distinct per quad, conflict-free.
// Grid (64 n-groups, 4 m-tiles of 128) = 256 blocks, 256 thr (4 waves, m-split).
__global__ __launch_bounds__(256, 1) void lstm_step_k(
    const short* __restrict__ h_prev, const short* __restrict__ Wh_t,
    const short* __restrict__ eproj, const int* __restrict__ msg, int t,
    float* __restrict__ c, short* __restrict__ h_next)
{
    extern __shared__ __align__(16) short Bs[];   // [128 k8][512] shorts = 128 KB
    const int tid  = threadIdx.x;
    const int lane = tid & 63, wid = tid >> 6;    // wave = m-slice of 32 rows
    const int col16 = lane & 15, quad = lane >> 4;
    const int m0 = blockIdx.x >= 0 ? blockIdx.y * 128 : 0;
    const int n0 = blockIdx.x * 64;
    const int mw = m0 + wid * 32;

    // ---- B staging: wave wid stages k8 = wid + 4*i (k8&3 == wid), swizzled ----
    // slot l holds logical row n = (l - 2*wid) & 63 of this k8-chunk.
    const int nl = (lane - 2 * wid) & 63;
    const short* bg = Wh_t + (size_t)(n0 + nl) * HID + wid * 8;
#pragma unroll
    for (int i = 0; i < 16; i++)                   // half 1: k8 in [0,64) -> k < 512
        async_cp16(&Bs[(wid + 4 * i) * 512], bg + i * 32);

    // gate preactivation gather + c-state load (overlaps DMA; consumed in epilogue)
    const int j = blockIdx.x * 16 + col16;
    float gi[2][4][4], cold[2][4];
#pragma unroll
    for (int tr = 0; tr < 2; tr++)
#pragma unroll
        for (int r = 0; r < 4; r++) {
            int b = mw + tr * 16 + quad * 4 + r;
            int v = msg[b * TT + t];
            const short* ep = eproj + (size_t)v * FOURH + n0 + col16;
#pragma unroll
            for (int tc = 0; tc < 4; tc++) gi[tr][tc][r] = bf2f(ep[tc * 16]);
            cold[tr][r] = c[(size_t)b * HID + j];
        }

    f32x4 acc[2][4];
#pragma unroll
    for (int i = 0; i < 2; i++)
#pragma unroll
        for (int jj = 0; jj < 4; jj++) acc[i][jj] = (f32x4)0.0f;

    const short* ap0 = h_prev + (size_t)(mw + col16) * HID + quad * 8;
    const short* ap1 = h_prev + (size_t)(mw + 16 + col16) * HID + quad * 8;
    const int bq0 = ((0 * 16 + col16 + 2 * quad) & 63) * 8;
    const int bq1 = ((1 * 16 + col16 + 2 * quad) & 63) * 8;
    const int bq2 = ((2 * 16 + col16 + 2 * quad) & 63) * 8;
    const int bq3 = ((3 * 16 + col16 + 2 * quad) & 63) * 8;

    __syncthreads();                               // half 1 resident

#pragma unroll
    for (int i = 16; i < 32; i++)                  // half 2: k8 in [64,128) -> k >= 512
        async_cp16(&Bs[(wid + 4 * i) * 512], bg + i * 32);

    // ---- planes 0..15 (k < 512), no barriers ----
#pragma unroll 4
    for (int p = 0; p < 16; p++) {
        short8 a0 = *(const short8*)(ap0 + p * 32);
        short8 a1 = *(const short8*)(ap1 + p * 32);
        const int kb = (4 * p + quad) * 512;
        short8 b0 = *(const short8*)&Bs[kb + bq0];
        short8 b1 = *(const short8*)&Bs[kb + bq1];
        short8 b2 = *(const short8*)&Bs[kb + bq2];
        short8 b3 = *(const short8*)&Bs[kb + bq3];
        acc[0][0] = __builtin_amdgcn_mfma_f32_16x16x32_bf16(a0, b0, acc[0][0], 0, 0, 0);
        acc[0][1] = __builtin_amdgcn_mfma_f32_16x16x32_bf16(a0, b1, acc[0][1], 0, 0, 0);
        acc[0][2] = __builtin_amdgcn_mfma_f32_16x16x32_bf16(a0, b2, acc[0][2], 0, 0, 0);
        acc[0][3] = __builtin_amdgcn_mfma_f32_16x16x32_bf16(a0, b3, acc[0][3], 0, 0, 0);
        acc[1][0] = __builtin_amdgcn_mfma_f32_16x16x32_bf16(a1, b0, acc[1][0], 0, 0, 0);
        acc[1][1] = __builtin_amdgcn_mfma_f32_16x16x32_bf16(a1, b1, acc[1][1], 0, 0, 0);
        acc[1][2] = __builtin_amdgcn_mfma_f32_16x16x32_bf16(a1, b2, acc[1][2], 0, 0, 0);
        acc[1][3] = __builtin_amdgcn_mfma_f32_16x16x32_bf16(a1, b3, acc[1][3], 0, 0, 0);
    }

    __syncthreads();                               // half 2 resident (drained behind loop 1)

    // ---- planes 16..31 (k >= 512), no barriers ----
#pragma unroll 4
    for (int p = 16; p < 32; p++) {
        short8 a0 = *(const short8*)(ap0 + p * 32);
        short8 a1 = *(const short8*)(ap1 + p * 32);
        const int kb = (4 * p + quad) * 512;
        short8 b0 = *(const short8*)&Bs[kb + bq0];
        short8 b1 = *(const short8*)&Bs[kb + bq1];
        short8 b2 = *(const short8*)&Bs[kb + bq2];
        short8 b3 = *(const short8*)&Bs[kb + bq3];
        acc[0][0] = __builtin_amdgcn_mfma_f32_16x16x32_bf16(a0, b0, acc[0][0], 0, 0, 0);
        acc[0][1] = __builtin_amdgcn_mfma_f32_16x16x32_bf16(a0, b1, acc[0][1], 0, 0, 0);
        acc[0][2] = __builtin_amdgcn_mfma_f32_16x16x32_bf16(a0, b2, acc[0][2], 0, 0, 0);
        acc[0][3] = __builtin_amdgcn_mfma_f32_16x16x32_bf16(a0, b3, acc[0][3], 0, 0, 0);
        acc[1][0] = __builtin_amdgcn_mfma_f32_16x16x32_bf16(a1, b0, acc[1][0], 0, 0, 0);
        acc[1][1] = __builtin_amdgcn_mfma_f32_16x16x32_bf16(a1, b1, acc[1][1], 0, 0, 0);
        acc[1][2] = __builtin_amdgcn_mfma_f32_16x16x32_bf16(a1, b2, acc[1][2], 0, 0, 0);
        acc[1][3] = __builtin_amdgcn_mfma_f32_16x16x32_bf16(a1, b3, acc[1][3], 0, 0, 0);
    }

    // fused cell update (tc == gate {i,g,f,o}); write c and h slice
#pragma unroll
    for (int tr = 0; tr < 2; tr++)
#pragma unroll
        for (int r = 0; r < 4; r++) {
            int b = mw + tr * 16 + quad * 4 + r;
            float i_ = acc[tr][0][r] + gi[tr][0][r];
            float g_ = acc[tr][1][r] + gi[tr][1][r];
            float f_ = acc[tr][2][r] + gi[tr][2][r];
            float o_ = acc[tr][3][r] + gi[tr][3][r];
            size_t idx = (size_t)b * HID + j;
            float cn = sigmoidf_(f_ + 1.0f) * cold[tr][r] + sigmoidf_(i_) * tanhf(g_);
            c[idx] = cn;
            h_next[idx] = f2bf(sigmoidf_(o_) * tanhf(cn));
        }
}

// ---------------------------------------------------------------------------
extern "C" void kernel_launch(void* const* d_in, const int* in_sizes, int n_in,
                              void* d_out, int out_size, void* d_ws, size_t ws_size,
                              hipStream_t stream) {
    const float* images = (const float*)d_in[0];
    const float* embed  = (const float*)d_in[1];
    const float* Wcell  = (const float*)d_in[2];
    const float* bcell  = (const float*)d_in[3];
    const float* Wimg   = (const float*)d_in[4];
    const float* bimg   = (const float*)d_in[5];
    const float* Whid   = (const float*)d_in[6];
    const float* bhid   = (const float*)d_in[7];
    const int*   msg    = (const int*)d_in[8];

    float* out0 = (float*)d_out;                   // images_encoded [512,1024] f32
    float* out1 = out0 + (size_t)BB * OUTN;        // hidden_encoded [512,1024] f32

    // Workspace layout (33 MB)
    char* ws = (char*)d_ws;
    const size_t MB = 1024 * 1024;
    short* Wh_t    = (short*)(ws);            //  8 MB [4096][1024] bf16, colmapped
    short* Wx_t    = (short*)(ws + 8 * MB);   //  4 MB [4096][512]  bf16, colmapped
    short* Wimg_t  = (short*)(ws + 12 * MB);  //  4 MB [1024][2048] bf16
    short* Whid_t  = (short*)(ws + 16 * MB);  //  2 MB [1024][1024] bf16
    short* eproj   = (short*)(ws + 18 * MB);  //  8 MB [1024][4096] bf16, bias folded
    short* h_a     = (short*)(ws + 26 * MB);  //  1 MB
    short* h_b     = (short*)(ws + 27 * MB);  //  1 MB
    float* cbuf    = (float*)(ws + 28 * MB);  //  2 MB
    short* imgs_c  = (short*)(ws + 30 * MB);  //  2 MB [512][2048] bf16
    short* embed_c = (short*)(ws + 32 * MB);  //  1 MB [1024][512] bf16

    // allow 128 KB dynamic LDS for the step kernel
    (void)hipFuncSetAttribute((const void*)lstm_step_k, hipFuncAttributeMaxDynamicSharedMemorySize, 131072);

    // merged setup: cvt images + cvt embed + state/out init (one launch)
    setup_k<<<dim3(3584), dim3(256), 0, stream>>>(
        images, imgs_c, embed, embed_c, cbuf, h_a, out0, out1, bimg, bhid);

    // merged weight transposes (one launch, 9216 tiles)
    tr_all_k<<<dim3(9216), dim3(256), 0, stream>>>(
        Wcell + (size_t)EMBD * FOURH, Wh_t, Wcell, Wx_t, Wimg, Wimg_t, Whid, Whid_t);

    // eproj = bf16(embed @ W_x + b_cell), gate-interleaved  (single launch, 512 blocks)
    gemm_bt_k<short, false, true><<<dim3(FOURH / 128, VOC / 64, 1), dim3(256), 0, stream>>>(
        embed_c, Wx_t, bcell, eproj, EMBD, EMBD / 64, FOURH);

    // images_encoded: split-K=4 in one launch (grid 8x8x4 = 256 blocks)
    gemm_bt_k<float, true, false><<<dim3(OUTN / 128, BB / 64, 4), dim3(256), 0, stream>>>(
        imgs_c, Wimg_t, nullptr, out0, DIMG, 8, OUTN);

    // 128 sequential LSTM steps, ping-pong h (t=127 writes h_a); 256 blocks = 1/CU
    for (int t = 0; t < TT; t++) {
        const short* hp = (t & 1) ? h_b : h_a;
        short* hn       = (t & 1) ? h_a : h_b;
        lstm_step_k<<<dim3(64, 4), dim3(256), 131072, stream>>>(
            hp, Wh_t, eproj, msg, t, cbuf, hn);
    }

    // hidden_encoded: split-K=4 in one launch
    gemm_bt_k<float, true, false><<<dim3(OUTN / 128, BB / 64, 4), dim3(256), 0, stream>>>(
        h_a, Whid_t, nullptr, out1, HID, 4, OUTN);
}

// Round 14
// 1908.374 us; speedup vs baseline: 1.4223x; 1.4223x over previous
//
#include <hip/hip_runtime.h>
#include <hip/hip_bf16.h>

// Problem constants (from reference)
#define BB    512
#define TT    128
#define HID   1024
#define EMBD  512
#define VOC   1024
#define OUTN  1024
#define DIMG  2048
#define FOURH 4096

typedef __attribute__((ext_vector_type(8))) short  short8;   // 8 bf16 (MFMA A/B frag)
typedef __attribute__((ext_vector_type(4))) float  f32x4;    // MFMA C/D frag
typedef unsigned int u32;

// Gate-interleaved column map: n' = G*64 + gate*16 + u -> original col = gate*1024 + G*16 + u
__device__ __forceinline__ int lstm_colmap(int n) {
    return ((n >> 4) & 3) * HID + ((n >> 6) << 4) + (n & 15);
}
__device__ __forceinline__ float sigmoidf_(float x) { return 1.0f / (1.0f + expf(-x)); }
__device__ __forceinline__ short f2bf(float x) { __hip_bfloat16 b = __float2bfloat16(x); return *(short*)&b; }
__device__ __forceinline__ float bf2f(short s) { __hip_bfloat16 b; *(short*)&b = s; return __bfloat162float(b); }

// async global->LDS, 16B per lane; lds base wave-uniform (HW adds lane*16)
__device__ __forceinline__ void async_cp16(void* lds, const void* g) {
    __builtin_amdgcn_global_load_lds((const __attribute__((address_space(1))) u32*)g,
                                     (__attribute__((address_space(3))) u32*)lds, 16, 0, 0);
}

// ---------------------------------------------------------------------------
// Merged prep (one launch): blocks [0,3584) do elementwise setup (cvt images,
// cvt embed, state init + bias broadcast); blocks [3584, 3584+9216) do the four
// tiled weight transposes out[n][k] = bf16(in[k][map?(n)]).
__global__ void prep_k(const float* __restrict__ images, short* __restrict__ imgs_c,
                       const float* __restrict__ embed,  short* __restrict__ embed_c,
                       float* __restrict__ c, short* __restrict__ h0,
                       float* __restrict__ o0, float* __restrict__ o1,
                       const float* __restrict__ bimg, const float* __restrict__ bhid,
                       const float* __restrict__ Wc_h, short* __restrict__ Wh_t,
                       const float* __restrict__ Wc_x, short* __restrict__ Wx_t,
                       const float* __restrict__ Wimg, short* __restrict__ Wimg_t,
                       const float* __restrict__ Whid, short* __restrict__ Whid_t) {
    if (blockIdx.x < 3584) {
        int i = blockIdx.x * 256 + threadIdx.x;
        if (i < 262144) {                       // images: 512*2048/4
            float4 v = ((const float4*)images)[i];
            short4 o; o.x = f2bf(v.x); o.y = f2bf(v.y); o.z = f2bf(v.z); o.w = f2bf(v.w);
            ((short4*)imgs_c)[i] = o;
        } else if (i < 393216) {                // embed: 1024*512/4
            int k = i - 262144;
            float4 v = ((const float4*)embed)[k];
            short4 o; o.x = f2bf(v.x); o.y = f2bf(v.y); o.z = f2bf(v.z); o.w = f2bf(v.w);
            ((short4*)embed_c)[k] = o;
        } else {                                // state/out init: 512*1024
            int k = i - 393216;
            int n = k & (OUTN - 1);
            c[k] = 0.0f; h0[k] = 0;
            o0[k] = bimg[n]; o1[k] = bhid[n];
        }
        return;
    }
    int id = blockIdx.x - 3584;
    const float* in; short* out; int K, N_in, bx, by; bool map;
    if (id < 4096)      { in = Wc_h; out = Wh_t;   K = 1024; N_in = 4096; map = true;  bx = id & 127;  by = id >> 7; }
    else if (id < 6144) { id -= 4096; in = Wc_x; out = Wx_t; K = 512;  N_in = 4096; map = true;  bx = id & 127;  by = id >> 7; }
    else if (id < 8192) { id -= 6144; in = Wimg; out = Wimg_t; K = 2048; N_in = 1024; map = false; bx = id & 31; by = id >> 5; }
    else                { id -= 8192; in = Whid; out = Whid_t; K = 1024; N_in = 1024; map = false; bx = id & 31; by = id >> 5; }

    __shared__ short tile[32][33];
    int n0 = bx * 32, k0 = by * 32;
    int tx = threadIdx.x & 31, ty = threadIdx.x >> 5;   // 32 x 8
    int nsrc = map ? lstm_colmap(n0 + tx) : (n0 + tx);
#pragma unroll
    for (int j = 0; j < 4; j++) {
        int kw = ty + j * 8;
        tile[kw][tx] = f2bf(in[(size_t)(k0 + kw) * N_in + nsrc]);
    }
    __syncthreads();
#pragma unroll
    for (int j = 0; j < 4; j++) {
        int nw = ty + j * 8;
        out[(size_t)(n0 + nw) * K + k0 + tx] = tile[tx][nw];
    }
}

// ---------------------------------------------------------------------------
// Double-buffered MFMA core, tile 64x128, BK=64, 4 waves 2x2 (R8/R9-verified; used
// for the three one-shot GEMMs only).
template<typename OutT, bool ATOMIC, bool MAPB>
__global__ __launch_bounds__(256) void gemm_bt_k(
    const short* __restrict__ A, const short* __restrict__ Bt,
    const float* __restrict__ bias, OutT* __restrict__ out,
    int Kf, int niter, int N)
{
    __shared__ __align__(16) short As[2][2][64 * 32];
    __shared__ __align__(16) short Bs[2][2][128 * 32];
    const int tid  = threadIdx.x;
    const int lane = tid & 63, wid = tid >> 6;
    const int wm = wid >> 1, wn = wid & 1;
    const int col16 = lane & 15, quad = lane >> 4;
    const int m0 = blockIdx.y * 64;
    const int n0 = blockIdx.x * 128;
    const int kbeg = blockIdx.z * niter * 64;

    const short* agp = A  + (size_t)(m0 + wid * 16 + (lane >> 2)) * Kf + kbeg + (lane & 3) * 8;
    const short* bgp = Bt + (size_t)(n0 + wid * 32 + (lane >> 2)) * Kf + kbeg + (lane & 3) * 8;

    f32x4 acc[2][4];
#pragma unroll
    for (int i = 0; i < 2; i++)
#pragma unroll
        for (int jj = 0; jj < 4; jj++) acc[i][jj] = (f32x4)0.0f;

    async_cp16(&As[0][0][wid * 512], agp);
    async_cp16(&As[0][1][wid * 512], agp + 32);
    async_cp16(&Bs[0][0][wid * 1024],       bgp);
    async_cp16(&Bs[0][0][wid * 1024 + 512], bgp + (size_t)16 * Kf);
    async_cp16(&Bs[0][1][wid * 1024],       bgp + 32);
    async_cp16(&Bs[0][1][wid * 1024 + 512], bgp + (size_t)16 * Kf + 32);
    __syncthreads();

    int buf = 0;
#pragma unroll 1
    for (int it = 0; it < niter; ++it) {
        if (it + 1 < niter) {
            int k0 = (it + 1) * 64;
            async_cp16(&As[buf ^ 1][0][wid * 512], agp + k0);
            async_cp16(&As[buf ^ 1][1][wid * 512], agp + k0 + 32);
            async_cp16(&Bs[buf ^ 1][0][wid * 1024],       bgp + k0);
            async_cp16(&Bs[buf ^ 1][0][wid * 1024 + 512], bgp + (size_t)16 * Kf + k0);
            async_cp16(&Bs[buf ^ 1][1][wid * 1024],       bgp + k0 + 32);
            async_cp16(&Bs[buf ^ 1][1][wid * 1024 + 512], bgp + (size_t)16 * Kf + k0 + 32);
        }
        short8 af[2][2], bf[4][2];
#pragma unroll
        for (int tr = 0; tr < 2; tr++)
#pragma unroll
            for (int p = 0; p < 2; p++)
                af[tr][p] = *(const short8*)&As[buf][p][(wm * 32 + tr * 16 + col16) * 32 + quad * 8];
#pragma unroll
        for (int tc = 0; tc < 4; tc++)
#pragma unroll
            for (int p = 0; p < 2; p++)
                bf[tc][p] = *(const short8*)&Bs[buf][p][(wn * 64 + tc * 16 + col16) * 32 + quad * 8];
#pragma unroll
        for (int p = 0; p < 2; p++)
#pragma unroll
            for (int tr = 0; tr < 2; tr++)
#pragma unroll
                for (int tc = 0; tc < 4; tc++)
                    acc[tr][tc] = __builtin_amdgcn_mfma_f32_16x16x32_bf16(af[tr][p], bf[tc][p], acc[tr][tc], 0, 0, 0);
        __syncthreads();
        buf ^= 1;
    }

#pragma unroll
    for (int tr = 0; tr < 2; tr++)
#pragma unroll
        for (int tc = 0; tc < 4; tc++) {
            int colg = n0 + wn * 64 + tc * 16 + col16;
            float bv = 0.0f;
            if constexpr (!ATOMIC) bv = bias[MAPB ? lstm_colmap(colg) : colg];
#pragma unroll
            for (int r = 0; r < 4; r++) {
                int rowg = m0 + wm * 32 + tr * 16 + quad * 4 + r;
                float v = acc[tr][tc][r] + bv;
                if constexpr (ATOMIC) atomicAdd((float*)&out[(size_t)rowg * N + colg], v);
                else                  out[(size_t)rowg * N + colg] = f2bf(v);
            }
        }
}

// ---------------------------------------------------------------------------
// LSTM step — EXACT R9/R11 kernel (global best, 13.1 us/step): BK=128 (4 k-planes),
// bank-conflict-free swizzled LDS (verified SQ_LDS_BANK_CONFLICT=0), 8 barriers/step.
// Swizzle: chunk q of row r stored at physical column ((q + (r>>1)) & 3) * 8 shorts.
__global__ __launch_bounds__(256) void lstm_step_k(
    const short* __restrict__ h_prev, const short* __restrict__ Wh_t,
    const short* __restrict__ eproj, const int* __restrict__ msg, int t,
    float* __restrict__ c, short* __restrict__ h_next)
{
    constexpr int Kf = HID;
    extern __shared__ __align__(16) short smem[];
    short* As = smem;           // [2][4][2048] shorts
    short* Bs = smem + 16384;   // [2][4][4096] shorts

    const int tid  = threadIdx.x;
    const int lane = tid & 63, wid = tid >> 6;
    const int wm = wid >> 1, wn = wid & 1;
    const int col16 = lane & 15, quad = lane >> 4;
    const int m0 = blockIdx.y * 64;
    const int n0 = blockIdx.x * 128;

    const int swz_st = (((lane & 3) - ((lane >> 3) & 3)) & 3) * 8;
    const short* agp  = h_prev + (size_t)(m0 + wid * 16 + (lane >> 2)) * Kf + swz_st;
    const short* bgp0 = Wh_t   + (size_t)(n0 + wid * 32 + (lane >> 2)) * Kf + swz_st;
    const short* bgp1 = bgp0 + (size_t)16 * Kf;

    // stage buf 0 (k = 0..127)
#pragma unroll
    for (int p = 0; p < 4; p++) {
        async_cp16(&As[p * 2048 + wid * 512], agp + p * 32);
        async_cp16(&Bs[p * 4096 + wid * 1024],       bgp0 + p * 32);
        async_cp16(&Bs[p * 4096 + wid * 1024 + 512], bgp1 + p * 32);
    }

    // gate preactivation gather + c-state load (overlap the DMA; consumed after K-loop)
    const int G = (n0 + wn * 64) >> 6;
    const int j = G * 16 + col16;
    float gi[2][4][4], cold[2][4];
#pragma unroll
    for (int tr = 0; tr < 2; tr++)
#pragma unroll
        for (int r = 0; r < 4; r++) {
            int b = m0 + wm * 32 + tr * 16 + quad * 4 + r;
            int v = msg[b * TT + t];
            const short* ep = eproj + (size_t)v * FOURH + n0 + wn * 64 + col16;
#pragma unroll
            for (int tc = 0; tc < 4; tc++) gi[tr][tc][r] = bf2f(ep[tc * 16]);
            cold[tr][r] = c[(size_t)b * HID + j];
        }

    f32x4 acc[2][4];
#pragma unroll
    for (int i = 0; i < 2; i++)
#pragma unroll
        for (int jj = 0; jj < 4; jj++) acc[i][jj] = (f32x4)0.0f;

    const int swz_rd = ((quad + (col16 >> 1)) & 3) * 8;
    const int arow = (wm * 32 + col16) * 32 + swz_rd;   // + tr*512
    const int brow = (wn * 64 + col16) * 32 + swz_rd;   // + tc*512

    __syncthreads();

    int buf = 0;
#pragma unroll 1
    for (int it = 0; it < 8; ++it) {
        if (it + 1 < 8) {
            const int k0 = (it + 1) * 128;
            const int bo = buf ^ 1;
#pragma unroll
            for (int p = 0; p < 4; p++) {
                async_cp16(&As[bo * 8192 + p * 2048 + wid * 512], agp + k0 + p * 32);
                async_cp16(&Bs[bo * 16384 + p * 4096 + wid * 1024],       bgp0 + k0 + p * 32);
                async_cp16(&Bs[bo * 16384 + p * 4096 + wid * 1024 + 512], bgp1 + k0 + p * 32);
            }
        }
        const short* Ab = &As[buf * 8192];
        const short* Bb = &Bs[buf * 16384];
#pragma unroll
        for (int p = 0; p < 4; p++) {
            short8 af0 = *(const short8*)&Ab[p * 2048 + arow];
            short8 af1 = *(const short8*)&Ab[p * 2048 + arow + 512];
            short8 bf0 = *(const short8*)&Bb[p * 4096 + brow];
            short8 bf1 = *(const short8*)&Bb[p * 4096 + brow + 512];
            short8 bf2 = *(const short8*)&Bb[p * 4096 + brow + 1024];
            short8 bf3 = *(const short8*)&Bb[p * 4096 + brow + 1536];
            acc[0][0] = __builtin_amdgcn_mfma_f32_16x16x32_bf16(af0, bf0, acc[0][0], 0, 0, 0);
            acc[0][1] = __builtin_amdgcn_mfma_f32_16x16x32_bf16(af0, bf1, acc[0][1], 0, 0, 0);
            acc[0][2] = __builtin_amdgcn_mfma_f32_16x16x32_bf16(af0, bf2, acc[0][2], 0, 0, 0);
            acc[0][3] = __builtin_amdgcn_mfma_f32_16x16x32_bf16(af0, bf3, acc[0][3], 0, 0, 0);
            acc[1][0] = __builtin_amdgcn_mfma_f32_16x16x32_bf16(af1, bf0, acc[1][0], 0, 0, 0);
            acc[1][1] = __builtin_amdgcn_mfma_f32_16x16x32_bf16(af1, bf1, acc[1][1], 0, 0, 0);
            acc[1][2] = __builtin_amdgcn_mfma_f32_16x16x32_bf16(af1, bf2, acc[1][2], 0, 0, 0);
            acc[1][3] = __builtin_amdgcn_mfma_f32_16x16x32_bf16(af1, bf3, acc[1][3], 0, 0, 0);
        }
        __syncthreads();
        buf ^= 1;
    }

    // fused cell update (tc == gate {i,g,f,o}); write c and h slice
#pragma unroll
    for (int tr = 0; tr < 2; tr++)
#pragma unroll
        for (int r = 0; r < 4; r++) {
            int b = m0 + wm * 32 + tr * 16 + quad * 4 + r;
            float i_ = acc[tr][0][r] + gi[tr][0][r];
            float g_ = acc[tr][1][r] + gi[tr][1][r];
            float f_ = acc[tr][2][r] + gi[tr][2][r];
            float o_ = acc[tr][3][r] + gi[tr][3][r];
            size_t idx = (size_t)b * HID + j;
            float cn = sigmoidf_(f_ + 1.0f) * cold[tr][r] + sigmoidf_(i_) * tanhf(g_);
            c[idx] = cn;
            h_next[idx] = f2bf(sigmoidf_(o_) * tanhf(cn));
        }
}

// ---------------------------------------------------------------------------
extern "C" void kernel_launch(void* const* d_in, const int* in_sizes, int n_in,
                              void* d_out, int out_size, void* d_ws, size_t ws_size,
                              hipStream_t stream) {
    const float* images = (const float*)d_in[0];
    const float* embed  = (const float*)d_in[1];
    const float* Wcell  = (const float*)d_in[2];
    const float* bcell  = (const float*)d_in[3];
    const float* Wimg   = (const float*)d_in[4];
    const float* bimg   = (const float*)d_in[5];
    const float* Whid   = (const float*)d_in[6];
    const float* bhid   = (const float*)d_in[7];
    const int*   msg    = (const int*)d_in[8];

    float* out0 = (float*)d_out;                   // images_encoded [512,1024] f32
    float* out1 = out0 + (size_t)BB * OUTN;        // hidden_encoded [512,1024] f32

    // Workspace layout (33 MB)
    char* ws = (char*)d_ws;
    const size_t MB = 1024 * 1024;
    short* Wh_t    = (short*)(ws);            //  8 MB [4096][1024] bf16, colmapped
    short* Wx_t    = (short*)(ws + 8 * MB);   //  4 MB [4096][512]  bf16, colmapped
    short* Wimg_t  = (short*)(ws + 12 * MB);  //  4 MB [1024][2048] bf16
    short* Whid_t  = (short*)(ws + 16 * MB);  //  2 MB [1024][1024] bf16
    short* eproj   = (short*)(ws + 18 * MB);  //  8 MB [1024][4096] bf16, bias folded
    short* h_a     = (short*)(ws + 26 * MB);  //  1 MB
    short* h_b     = (short*)(ws + 27 * MB);  //  1 MB
    float* cbuf    = (float*)(ws + 28 * MB);  //  2 MB
    short* imgs_c  = (short*)(ws + 30 * MB);  //  2 MB [512][2048] bf16
    short* embed_c = (short*)(ws + 32 * MB);  //  1 MB [1024][512] bf16

    // allow 96 KB dynamic LDS for the step kernel
    (void)hipFuncSetAttribute((const void*)lstm_step_k, hipFuncAttributeMaxDynamicSharedMemorySize, 98304);

    // merged prep: elementwise setup + all four weight transposes (one launch)
    prep_k<<<dim3(3584 + 9216), dim3(256), 0, stream>>>(
        images, imgs_c, embed, embed_c, cbuf, h_a, out0, out1, bimg, bhid,
        Wcell + (size_t)EMBD * FOURH, Wh_t, Wcell, Wx_t, Wimg, Wimg_t, Whid, Whid_t);

    // eproj = bf16(embed @ W_x + b_cell), gate-interleaved  (single launch, 512 blocks)
    gemm_bt_k<short, false, true><<<dim3(FOURH / 128, VOC / 64, 1), dim3(256), 0, stream>>>(
        embed_c, Wx_t, bcell, eproj, EMBD, EMBD / 64, FOURH);

    // images_encoded: split-K=4 in one launch (grid 8x8x4 = 256 blocks)
    gemm_bt_k<float, true, false><<<dim3(OUTN / 128, BB / 64, 4), dim3(256), 0, stream>>>(
        imgs_c, Wimg_t, nullptr, out0, DIMG, 8, OUTN);

    // 128 sequential LSTM steps, ping-pong h (t=127 writes h_a)
    for (int t = 0; t < TT; t++) {
        const short* hp = (t & 1) ? h_b : h_a;
        short* hn       = (t & 1) ? h_a : h_b;
        lstm_step_k<<<dim3(FOURH / 128, BB / 64), dim3(256), 98304, stream>>>(
            hp, Wh_t, eproj, msg, t, cbuf, hn);
    }

    // hidden_encoded: split-K=4 in one launch
    gemm_bt_k<float, true, false><<<dim3(OUTN / 128, BB / 64, 4), dim3(256), 0, stream>>>(
        h_a, Whid_t, nullptr, out1, HID, 4, OUTN);
}